// Round 2
// baseline (3361.243 us; speedup 1.0000x reference)
//
#include <hip/hip_runtime.h>
#include <math.h>

#define NEGV -1000000000.0f
#define EPSV 1e-38f

constexpr int B = 16, T = 32, K = 512, N = 24, V = 32000, H = 128;
constexpr int N2 = N * N;     // 576
constexpr int TRI = (T * (T + 1)) / 2;  // 528

__device__ __forceinline__ int tri(int i, int j) { return ((j * (j + 1)) >> 1) + i; }

// ---------------------------------------------------------------- frontend
__global__ void __launch_bounds__(128) frontend_kernel(
    const float* __restrict__ g_seq, const float* __restrict__ ln_gamma,
    const float* __restrict__ ln_beta, const float* __restrict__ W1,
    const float* __restrict__ b1, const float* __restrict__ W2,
    const float* __restrict__ b2, float* __restrict__ Phi) {
  int bt = blockIdx.x;
  int b = bt >> 5, t = bt & 31;
  int tid = threadIdx.x;
  __shared__ __align__(16) float g[K];
  __shared__ float red[128];
  __shared__ float hbuf[H];
  __shared__ float obuf[N];
  __shared__ float stats[2];

  float4 v = ((const float4*)(g_seq + bt * K))[tid];
  ((float4*)g)[tid] = v;
  float s = v.x + v.y + v.z + v.w;
  float sq = v.x * v.x + v.y * v.y + v.z * v.z + v.w * v.w;

  red[tid] = s; __syncthreads();
  for (int off = 64; off > 0; off >>= 1) { if (tid < off) red[tid] += red[tid + off]; __syncthreads(); }
  if (tid == 0) stats[0] = red[0] / (float)K;
  __syncthreads();
  red[tid] = sq; __syncthreads();
  for (int off = 64; off > 0; off >>= 1) { if (tid < off) red[tid] += red[tid + off]; __syncthreads(); }
  if (tid == 0) {
    float mu = stats[0];
    float var = red[0] / (float)K - mu * mu;
    stats[1] = rsqrtf(var + 1e-5f);
  }
  __syncthreads();
  float mu = stats[0], rstd = stats[1];
  for (int c = tid; c < K; c += 128)
    g[c] = (g[c] - mu) * rstd * ln_gamma[c] + ln_beta[c];
  __syncthreads();

  float acc = b1[tid];
  for (int c = 0; c < K; c++) acc = fmaf(g[c], W1[c * H + tid], acc);
  float ge = 0.5f * acc * (1.0f + erff(acc * 0.70710678118654752f));
  hbuf[tid] = ge;
  __syncthreads();

  if (tid < N) {
    float o = b2[tid];
    for (int jj = 0; jj < H; jj++) o = fmaf(hbuf[jj], W2[jj * N + tid], o);
    obuf[tid] = o;
  }
  __syncthreads();
  if (tid == 0) {
    float m = obuf[0];
    for (int n = 1; n < N; n++) m = fmaxf(m, obuf[n]);
    float ssum = 0.f;
    for (int n = 0; n < N; n++) ssum += expf(obuf[n] - m);
    stats[0] = m + logf(ssum);
  }
  __syncthreads();
  if (tid < N) Phi[(b * N + tid) * T + t] = obuf[tid] - stats[0];
}

// ---------------------------------------------------------------- theta prep
__global__ void theta_prep(const float* __restrict__ Theta,
                           float* __restrict__ et, float* __restrict__ etT,
                           float* __restrict__ tmv) {
  int tid = threadIdx.x; // 0..575 (row = x*N+y)
  __shared__ float wmax[9];
  const float* row = Theta + tid * N;
  float vals[N];
  float m = row[0];
  for (int z = 1; z < N; z++) m = fmaxf(m, row[z]);
  float ssum = 0.f;
  for (int z = 0; z < N; z++) { vals[z] = row[z]; ssum += expf(row[z] - m); }
  float lse = m + logf(ssum);
  float rmax = m - lse;

  float wm = rmax;
  for (int off = 32; off > 0; off >>= 1) wm = fmaxf(wm, __shfl_down(wm, off));
  if ((tid & 63) == 0) wmax[tid >> 6] = wm;
  __syncthreads();
  if (tid == 0) {
    float tm = wmax[0];
    for (int w = 1; w < 9; w++) tm = fmaxf(tm, wmax[w]);
    wmax[0] = tm;
    tmv[0] = tm;
  }
  __syncthreads();
  float tm = wmax[0];
  int x = tid / N, y = tid - (tid / N) * N;
  for (int z = 0; z < N; z++) {
    float e = expf(vals[z] - lse - tm);
    et[tid * N + z] = e;
    etT[(y * N + z) * N + x] = e;
  }
}

// ---------------------------------------------------------------- fused chart
// One block per batch. beta/alpha triangles + per-wave scratch live in LDS.
// Inside: 31 levels, 1 sync each. Outside: 31 levels x (cL phase, cR phase).
__global__ void __launch_bounds__(1024, 1) chart_kernel(
    const float* __restrict__ et, const float* __restrict__ etT,
    const float* __restrict__ tmv, const float* __restrict__ Phi,
    float* __restrict__ pnt, float* __restrict__ logZ_g) {
  __shared__ __align__(16) float beta_t[TRI * N];   // 12672 floats
  __shared__ __align__(16) float alpha_t[TRI * N];  // 12672 floats
  __shared__ __align__(16) float scr[12288];        // per-wave scratch
  int b = blockIdx.x;
  int tid = threadIdx.x;
  int lane = tid & 63, wid = tid >> 6;  // 16 waves
  int h = lane / 24;                    // 0,1 active for r/w compute; 2 idle
  int y24 = lane - 24 * h;
  float tm = tmv[0];

  // init
  for (int idx = tid; idx < TRI * N; idx += 1024) alpha_t[idx] = NEGV;
  for (int idx = tid; idx < N * T; idx += 1024) {
    int n = idx >> 5, t = idx & 31;
    beta_t[tri(t, t) * N + n] = Phi[(b * N + n) * T + t];
  }
  __syncthreads();
  if (tid == 0) alpha_t[tri(0, T - 1) * N + 0] = 0.f;
  __syncthreads();

  // ---------------- inside
  for (int l = 2; l <= T; l++) {
    int S = l - 1, P = T - l + 1;
    int SN = S * N;
    int slotStride = (2 * SN > N2) ? 2 * SN : N2;
    for (int i = wid; i < P; i += 16) {
      int j = i + S;
      float* sl = scr + wid * slotStride;
      float* eA = sl;
      float* eB = sl + SN;
      // raw load of left/right child rows
      for (int idx = lane; idx < SN; idx += 64) {
        int s = idx / N, y = idx - s * N;
        eA[idx] = beta_t[tri(i, i + s) * N + y];
        eB[idx] = beta_t[tri(i + s + 1, j) * N + y];
      }
      __builtin_amdgcn_wave_barrier();
      // per-split maxes (lane s < S)
      float mr_s = NEGV, msum = NEGV;
      if (lane < S) {
        float ml = NEGV;
        for (int y = 0; y < N; y++) {
          ml = fmaxf(ml, eA[lane * N + y]);
          mr_s = fmaxf(mr_s, eB[lane * N + y]);
        }
        msum = ml + mr_s;
      }
      float M = msum;
#pragma unroll
      for (int off = 32; off; off >>= 1) M = fmaxf(M, __shfl_xor(M, off));
      // exp in place (uniform loop so shfl stays convergent)
      int nIter = (SN + 63) >> 6;
      for (int it = 0; it < nIter; it++) {
        int idx = (it << 6) + lane;
        int s = idx / N; if (s >= S) s = S - 1;
        float mrs = __shfl(mr_s, s);
        if (idx < SN) {
          eA[idx] = __expf(eA[idx] + mrs - M);
          eB[idx] = __expf(eB[idx] - mrs);
        }
      }
      __builtin_amdgcn_wave_barrier();
      // r[y,z] = sum_s eA[s,y]*eB[s,z]; lane (h,y24) owns 12 z's
      float rv[12];
      if (h < 2) {
#pragma unroll
        for (int q = 0; q < 12; q++) rv[q] = 0.f;
        for (int s = 0; s < S; s++) {
          float a = eA[s * N + y24];
          const float4* b4 = (const float4*)(eB + s * N + 12 * h);
          float4 b0 = b4[0], b1 = b4[1], b2 = b4[2];
          rv[0] = fmaf(a, b0.x, rv[0]); rv[1] = fmaf(a, b0.y, rv[1]);
          rv[2] = fmaf(a, b0.z, rv[2]); rv[3] = fmaf(a, b0.w, rv[3]);
          rv[4] = fmaf(a, b1.x, rv[4]); rv[5] = fmaf(a, b1.y, rv[5]);
          rv[6] = fmaf(a, b1.z, rv[6]); rv[7] = fmaf(a, b1.w, rv[7]);
          rv[8] = fmaf(a, b2.x, rv[8]); rv[9] = fmaf(a, b2.y, rv[9]);
          rv[10] = fmaf(a, b2.z, rv[10]); rv[11] = fmaf(a, b2.w, rv[11]);
        }
      }
      __builtin_amdgcn_wave_barrier();
      if (h < 2) {
        float4* dst = (float4*)(sl + y24 * N + 12 * h);
        dst[0] = make_float4(rv[0], rv[1], rv[2], rv[3]);
        dst[1] = make_float4(rv[4], rv[5], rv[6], rv[7]);
        dst[2] = make_float4(rv[8], rv[9], rv[10], rv[11]);
      }
      __builtin_amdgcn_wave_barrier();
      // score[x] = sum_p et[x,p] * r[p]; lane (x=lane&31, half=lane>>5)
      int x = lane & 31, half = lane >> 5;
      float sc = 0.f;
      if (x < 24) {
        const float4* e4 = (const float4*)(et + x * N2 + half * 288);
        const float4* r4 = (const float4*)(sl + half * 288);
#pragma unroll 4
        for (int q = 0; q < 72; q++) {
          float4 a = e4[q], c = r4[q];
          sc = fmaf(a.x, c.x, fmaf(a.y, c.y, fmaf(a.z, c.z, fmaf(a.w, c.w, sc))));
        }
      }
      sc += __shfl_xor(sc, 32);
      if (lane < 24)
        beta_t[tri(i, j) * N + lane] = tm + M + __logf(fmaxf(sc, EPSV));
    }
    __syncthreads();
  }

  // ---------------- outside
  for (int l = T; l >= 2; l--) {
    int S = l - 1, P = T - l + 1;
    float* slot = scr + wid * N2;
    // ---- phase A: w + cL updates (targets unique across parents)
    for (int i = wid; i < P; i += 16) {
      int j = i + S;
      float av = (lane < 24) ? alpha_t[tri(i, j) * N + lane] : NEGV;
      float ma = av;
#pragma unroll
      for (int off = 32; off; off >>= 1) ma = fmaxf(ma, __shfl_xor(ma, off));
      float eav = (lane < 24) ? __expf(av - ma) : 0.f;
      if (h < 2) {
        int zb = 12 * h;
        float wl[12];
#pragma unroll
        for (int z = 0; z < 12; z++) {
          const float4* e4 = (const float4*)(etT + (y24 * N + zb + z) * N);
          float acc = 0.f;
#pragma unroll
          for (int xq = 0; xq < 6; xq++) {
            float4 e = e4[xq];
            acc = fmaf(e.x, __shfl(eav, 4 * xq + 0),
                  fmaf(e.y, __shfl(eav, 4 * xq + 1),
                  fmaf(e.z, __shfl(eav, 4 * xq + 2),
                  fmaf(e.w, __shfl(eav, 4 * xq + 3), acc))));
          }
          wl[z] = acc;
        }
        float4* dst = (float4*)(slot + y24 * N + zb);
        dst[0] = make_float4(wl[0], wl[1], wl[2], wl[3]);
        dst[1] = make_float4(wl[4], wl[5], wl[6], wl[7]);
        dst[2] = make_float4(wl[8], wl[9], wl[10], wl[11]);
      }
      __builtin_amdgcn_wave_barrier();
      for (int s = 0; s < S; s++) {
        float rbv = (lane < 24) ? beta_t[tri(i + s + 1, j) * N + lane] : NEGV;
        float mrb = rbv;
#pragma unroll
        for (int off = 32; off; off >>= 1) mrb = fmaxf(mrb, __shfl_xor(mrb, off));
        float erb = (lane < 24) ? __expf(rbv - mrb) : 0.f;
        if (lane < 24) {
          const float4* w4 = (const float4*)(slot + lane * N);
          float acc = 0.f;
#pragma unroll
          for (int zq = 0; zq < 6; zq++) {
            float4 w = w4[zq];
            acc = fmaf(w.x, __shfl(erb, 4 * zq + 0),
                  fmaf(w.y, __shfl(erb, 4 * zq + 1),
                  fmaf(w.z, __shfl(erb, 4 * zq + 2),
                  fmaf(w.w, __shfl(erb, 4 * zq + 3), acc))));
          }
          float cl = __logf(fmaxf(acc, EPSV)) + tm + ma + mrb;
          float* tgt = &alpha_t[tri(i, i + s) * N + lane];
          float old = *tgt;
          float mx = fmaxf(old, cl), mn = fminf(old, cl);
          *tgt = mx + log1pf(__expf(mn - mx));
        }
      }
    }
    __syncthreads();
    // ---- phase B: cR updates; reverse order so last phase-A parent reuses w
    if (wid < P) {
      int i1 = wid + 16;
      int cnt = (i1 < P) ? 2 : 1;
      for (int oi = 0; oi < cnt; oi++) {
        int i = (cnt == 2 && oi == 0) ? i1 : wid;
        bool recompute = (cnt == 2 && oi == 1);
        int j = i + S;
        float av = (lane < 24) ? alpha_t[tri(i, j) * N + lane] : NEGV;
        float ma = av;
#pragma unroll
        for (int off = 32; off; off >>= 1) ma = fmaxf(ma, __shfl_xor(ma, off));
        if (recompute) {
          float eav = (lane < 24) ? __expf(av - ma) : 0.f;
          if (h < 2) {
            int zb = 12 * h;
            float wl[12];
#pragma unroll
            for (int z = 0; z < 12; z++) {
              const float4* e4 = (const float4*)(etT + (y24 * N + zb + z) * N);
              float acc = 0.f;
#pragma unroll
              for (int xq = 0; xq < 6; xq++) {
                float4 e = e4[xq];
                acc = fmaf(e.x, __shfl(eav, 4 * xq + 0),
                      fmaf(e.y, __shfl(eav, 4 * xq + 1),
                      fmaf(e.z, __shfl(eav, 4 * xq + 2),
                      fmaf(e.w, __shfl(eav, 4 * xq + 3), acc))));
              }
              wl[z] = acc;
            }
            float4* dst = (float4*)(slot + y24 * N + zb);
            dst[0] = make_float4(wl[0], wl[1], wl[2], wl[3]);
            dst[1] = make_float4(wl[4], wl[5], wl[6], wl[7]);
            dst[2] = make_float4(wl[8], wl[9], wl[10], wl[11]);
          }
        }
        __builtin_amdgcn_wave_barrier();
        for (int s = 0; s < S; s++) {
          float lbv = (lane < 24) ? beta_t[tri(i, i + s) * N + lane] : NEGV;
          float mlb = lbv;
#pragma unroll
          for (int off = 32; off; off >>= 1) mlb = fmaxf(mlb, __shfl_xor(mlb, off));
          float elb = (lane < 24) ? __expf(lbv - mlb) : 0.f;
          if (lane < 24) {
            float acc = 0.f;
#pragma unroll
            for (int yy = 0; yy < 24; yy++)
              acc = fmaf(slot[yy * N + lane], __shfl(elb, yy), acc);
            float cr = __logf(fmaxf(acc, EPSV)) + tm + ma + mlb;
            float* tgt = &alpha_t[tri(i + s + 1, j) * N + lane];
            float old = *tgt;
            float mx = fmaxf(old, cr), mn = fminf(old, cr);
            *tgt = mx + log1pf(__expf(mn - mx));
          }
        }
      }
    }
    __syncthreads();
  }

  // ---------------- epilogue: p_nt and logZ
  float logZ = beta_t[tri(0, T - 1) * N + 0];
  if (tid < N * T) {
    int n = tid >> 5, t = tid & 31;
    int c = tri(t, t) * N + n;
    pnt[b * N * T + tid] = __expf(alpha_t[c] + beta_t[c] - logZ);
  }
  if (tid == 0) logZ_g[b] = logZ;
}

// ---------------------------------------------------------------- mask logits
__global__ void __launch_bounds__(256) mask_kernel(
    const float* __restrict__ pnt, const float* __restrict__ vocab,
    const float* __restrict__ logZ_g, float* __restrict__ out) {
  int b = blockIdx.y;
  int v = blockIdx.x * 256 + threadIdx.x;  // V = 125*256
  __shared__ float p[N * T];
  for (int idx = threadIdx.x; idx < N * T; idx += 256) p[idx] = pnt[b * N * T + idx];
  __syncthreads();
  float vr[N];
#pragma unroll
  for (int n = 0; n < N; n++) vr[n] = vocab[n * V + v];
  float* ob = out + (size_t)b * T * V + v;
  for (int t = 0; t < T; t++) {
    float acc = 1e-6f;
#pragma unroll
    for (int n = 0; n < N; n++) acc = fmaf(p[n * T + t], vr[n], acc);
    ob[(size_t)t * V] = logf(acc);
  }
  if (blockIdx.x == 0 && b == 0 && threadIdx.x == 0) {
    float ssum = 0.f;
    for (int bb = 0; bb < B; bb++) ssum += logZ_g[bb];
    out[(size_t)B * T * V] = -ssum / (float)B;
  }
}

// ---------------------------------------------------------------- launch
extern "C" void kernel_launch(void* const* d_in, const int* in_sizes, int n_in,
                              void* d_out, int out_size, void* d_ws, size_t ws_size,
                              hipStream_t stream) {
  const float* g_seq   = (const float*)d_in[0];
  const float* Theta   = (const float*)d_in[1];
  const float* vocab   = (const float*)d_in[2];
  const float* ln_g    = (const float*)d_in[3];
  const float* ln_b    = (const float*)d_in[4];
  const float* W1      = (const float*)d_in[5];
  const float* b1      = (const float*)d_in[6];
  const float* W2      = (const float*)d_in[7];
  const float* b2      = (const float*)d_in[8];
  float* out = (float*)d_out;

  float* ws   = (float*)d_ws;
  float* Phi  = ws;               // 12288
  float* et   = Phi + 12288;      // 13824
  float* etT  = et + 13824;       // 13824
  float* tmv  = etT + 13824;      // 16
  float* pnt  = tmv + 16;         // 12288
  float* logZ = pnt + 12288;      // 16

  frontend_kernel<<<dim3(B * T), dim3(128), 0, stream>>>(g_seq, ln_g, ln_b, W1, b1, W2, b2, Phi);
  theta_prep<<<dim3(1), dim3(576), 0, stream>>>(Theta, et, etT, tmv);
  chart_kernel<<<dim3(B), dim3(1024), 0, stream>>>(et, etT, tmv, Phi, pnt, logZ);
  mask_kernel<<<dim3(125, B), dim3(256), 0, stream>>>(pnt, vocab, logZ, out);
}

// Round 3
// 995.932 us; speedup vs baseline: 3.3750x; 3.3750x over previous
//
#include <hip/hip_runtime.h>
#include <math.h>

#define NEGV -1000000000.0f
#define EPSV 1e-38f

constexpr int TRIN = 528 * 24;  // floats per batch chart

__device__ __forceinline__ int tri(int i, int j) { return ((j * (j + 1)) >> 1) + i; }
__device__ __forceinline__ float la2(float a, float c) {
  float mx = fmaxf(a, c), mn = fminf(a, c);
  return mx + log1pf(__expf(mn - mx));
}

__device__ __forceinline__ void batch_bar(unsigned* c, unsigned tgt) {
  __syncthreads();
  if (threadIdx.x == 0) {
    __hip_atomic_fetch_add(c, 1u, __ATOMIC_RELEASE, __HIP_MEMORY_SCOPE_AGENT);
    while (__hip_atomic_load(c, __ATOMIC_RELAXED, __HIP_MEMORY_SCOPE_AGENT) < tgt)
      __builtin_amdgcn_s_sleep(2);
    (void)__hip_atomic_load(c, __ATOMIC_ACQUIRE, __HIP_MEMORY_SCOPE_AGENT);
  }
  __syncthreads();
}

// 512 blocks x 256 threads, cooperative. b = blk&15, local = blk>>4 (XCD-affine).
__global__ void __launch_bounds__(256, 2) mega_kernel(
    const float* __restrict__ g_seq, const float* __restrict__ Theta,
    const float* __restrict__ vocab, const float* __restrict__ lng,
    const float* __restrict__ lnb, const float* __restrict__ W1,
    const float* __restrict__ bb1, const float* __restrict__ W2,
    const float* __restrict__ bb2, float* __restrict__ out,
    float* __restrict__ et_g, float* __restrict__ beta_g,
    float* __restrict__ aL_g, float* __restrict__ aR_g,
    unsigned* __restrict__ cnt, float* __restrict__ logZg) {
  __shared__ __align__(16) float sm[16160];
  float* etL = sm;          // 13824: et resident in LDS for all chart phases
  float* wk = sm + 13824;   // 2336 workspace
  const int tid = threadIdx.x;
  const int blk = blockIdx.x;
  const int b = blk & 15, local = blk >> 4;
  unsigned* gcnt = cnt;
  unsigned* done = cnt + 32;
  unsigned* bcnt = cnt + 64 + b * 32;
  float* bbase = beta_g + b * TRIN;
  float* aLb = aL_g + b * TRIN;
  float* aRb = aR_g + b * TRIN;

  //================ phase 0: frontend, task bt = blk ================
  {
    float* g = wk;                       // 512
    float2* red = (float2*)(wk + 512);   // 256 float2 (512 floats)
    float* hb = wk + 1024;               // 128
    float* ob = wk + 1152;               // 32
    float* sc = wk + 1184;               // 8
    int bt = blk;
    float2 raw = ((const float2*)(g_seq + (size_t)bt * 512))[tid];
    red[tid] = make_float2(raw.x + raw.y, raw.x * raw.x + raw.y * raw.y);
    __syncthreads();
    if (tid < 128) { float2 o = red[tid + 128], m = red[tid]; red[tid] = make_float2(m.x + o.x, m.y + o.y); }
    __syncthreads();
    if (tid < 64) {
      float2 v = red[tid], o = red[tid + 64];
      v.x += o.x; v.y += o.y;
      for (int off = 32; off; off >>= 1) { v.x += __shfl_xor(v.x, off); v.y += __shfl_xor(v.y, off); }
      if (tid == 0) {
        float mu = v.x / 512.0f;
        float var = v.y / 512.0f - mu * mu;
        sc[0] = mu; sc[1] = rsqrtf(var + 1e-5f);
      }
    }
    __syncthreads();
    float mu = sc[0], rstd = sc[1];
    g[2 * tid]     = (raw.x - mu) * rstd * lng[2 * tid]     + lnb[2 * tid];
    g[2 * tid + 1] = (raw.y - mu) * rstd * lng[2 * tid + 1] + lnb[2 * tid + 1];
    __syncthreads();
    {
      int j = tid & 127, hh = tid >> 7, c0 = hh * 256;
      float a0 = 0, a1 = 0, a2 = 0, a3 = 0;
      for (int c = 0; c < 256; c += 4) {
        a0 = fmaf(g[c0 + c],     W1[(c0 + c) * 128 + j],     a0);
        a1 = fmaf(g[c0 + c + 1], W1[(c0 + c + 1) * 128 + j], a1);
        a2 = fmaf(g[c0 + c + 2], W1[(c0 + c + 2) * 128 + j], a2);
        a3 = fmaf(g[c0 + c + 3], W1[(c0 + c + 3) * 128 + j], a3);
      }
      ((float*)red)[tid] = (a0 + a1) + (a2 + a3);
    }
    __syncthreads();
    if (tid < 128) {
      float a = ((float*)red)[tid] + ((float*)red)[tid + 128] + bb1[tid];
      hb[tid] = 0.5f * a * (1.0f + erff(a * 0.70710678118654752f));
    }
    __syncthreads();
    if (tid < 192) {
      int n = tid >> 3, q = tid & 7;
      float a = 0;
      for (int k = 0; k < 16; k++) a = fmaf(hb[q * 16 + k], W2[(q * 16 + k) * 24 + n], a);
      ((float*)red)[tid] = a;
    }
    __syncthreads();
    if (tid < 24) {
      float a = bb2[tid];
      for (int q = 0; q < 8; q++) a += ((float*)red)[tid * 8 + q];
      ob[tid] = a;
    }
    __syncthreads();
    if (tid == 0) {
      float m = ob[0];
      for (int n = 1; n < 24; n++) m = fmaxf(m, ob[n]);
      float s = 0;
      for (int n = 0; n < 24; n++) s += __expf(ob[n] - m);
      sc[2] = m + __logf(s);
    }
    __syncthreads();
    if (tid < 24) {
      int fb = bt >> 5, ft = bt & 31;
      beta_g[(size_t)fb * TRIN + tri(ft, ft) * 24 + tid] = ob[tid] - sc[2];
    }
  }
  // theta rows (tm dropped: exact since score adds log back; et=exp(theta_log)<=1)
  if (tid < 64) {
    int z = tid & 31;
    bool up = tid >= 32;
    int row = up ? (512 + blk) : blk;
    bool valid = (!up) || (blk < 64);
    float v = (z < 24 && valid) ? Theta[row * 24 + z] : NEGV;
    float m = v;
    for (int off = 16; off; off >>= 1) m = fmaxf(m, __shfl_xor(m, off));
    float e = (z < 24 && valid) ? __expf(v - m) : 0.f;
    float s = e;
    for (int off = 16; off; off >>= 1) s += __shfl_xor(s, off);
    float lse = m + __logf(s);
    if (z < 24 && valid) et_g[row * 24 + z] = __expf(v - lse);
  }
  // alpha split-buffer init (aL||aR contiguous); root cell aL[b][tri(0,31)][0]=0
  for (int idx = blk * 256 + tid; idx < 405504; idx += 131072) {
    float v = NEGV;
    if (idx < 202752 && (idx % 12672) == 11904) v = 0.f;
    aL_g[idx] = v;
  }
  // ---- global barrier (two-stage: per-batch then root) ----
  __syncthreads();
  if (tid == 0) {
    __hip_atomic_fetch_add(bcnt, 1u, __ATOMIC_RELEASE, __HIP_MEMORY_SCOPE_AGENT);
    if (local == 0) {
      while (__hip_atomic_load(bcnt, __ATOMIC_RELAXED, __HIP_MEMORY_SCOPE_AGENT) < 32u)
        __builtin_amdgcn_s_sleep(2);
      (void)__hip_atomic_load(bcnt, __ATOMIC_ACQUIRE, __HIP_MEMORY_SCOPE_AGENT);
      __hip_atomic_fetch_add(gcnt, 1u, __ATOMIC_RELEASE, __HIP_MEMORY_SCOPE_AGENT);
    }
    while (__hip_atomic_load(gcnt, __ATOMIC_RELAXED, __HIP_MEMORY_SCOPE_AGENT) < 16u)
      __builtin_amdgcn_s_sleep(2);
    (void)__hip_atomic_load(gcnt, __ATOMIC_ACQUIRE, __HIP_MEMORY_SCOPE_AGENT);
  }
  __syncthreads();
  unsigned tgt = 64;

  // stage et into LDS once (immune to barrier cache invalidates)
  for (int i4 = tid; i4 < 3456; i4 += 256)
    ((float4*)etL)[i4] = ((const float4*)et_g)[i4];
  __syncthreads();

  //================ inside: 31 levels, block = span local ================
  {
    float* eA = wk;           // 744
    float* eB = wk + 744;     // 744
    float* rr = wk + 1488;    // 576
    float* red2 = wk + 2064;  // 192
    float* mrl = wk + 2256;   // 32
    float* msm = wk + 2288;   // 32
    float* scal = wk + 2320;  // 16
    for (int l = 2; l <= 32; l++) {
      int S = l - 1, P = 33 - l;
      if (local < P) {
        int i = local, j = i + S, SN = S * 24;
        for (int idx = tid; idx < SN; idx += 256) {
          int s = idx / 24, y = idx - s * 24;
          eA[idx] = bbase[tri(i, i + s) * 24 + y];
          eB[idx] = bbase[tri(i + s + 1, j) * 24 + y];
        }
        __syncthreads();
        if (tid < 8 * S) {
          int s = tid >> 3, q = tid & 7, y0 = q * 3;
          float pa = fmaxf(fmaxf(eA[s * 24 + y0], eA[s * 24 + y0 + 1]), eA[s * 24 + y0 + 2]);
          float pb = fmaxf(fmaxf(eB[s * 24 + y0], eB[s * 24 + y0 + 1]), eB[s * 24 + y0 + 2]);
          for (int off = 4; off; off >>= 1) {
            pa = fmaxf(pa, __shfl_xor(pa, off));
            pb = fmaxf(pb, __shfl_xor(pb, off));
          }
          if (q == 0) { mrl[s] = pb; msm[s] = pa + pb; }
        }
        __syncthreads();
        if (tid < 32) {
          float v = (tid < S) ? msm[tid] : NEGV;
          for (int off = 16; off; off >>= 1) v = fmaxf(v, __shfl_xor(v, off));
          if (tid == 0) scal[0] = v;
        }
        __syncthreads();
        float M = scal[0];
        for (int idx = tid; idx < SN; idx += 256) {
          int s = idx / 24;
          float m_ = mrl[s];
          eA[idx] = __expf(eA[idx] + m_ - M);
          eB[idx] = __expf(eB[idx] - m_);
        }
        __syncthreads();
        if (tid < 144) {
          int y = tid / 6, zq = tid % 6;
          float4 acc = make_float4(0, 0, 0, 0);
          for (int s = 0; s < S; s++) {
            float a = eA[s * 24 + y];
            float4 b4 = ((float4*)eB)[s * 6 + zq];
            acc.x = fmaf(a, b4.x, acc.x); acc.y = fmaf(a, b4.y, acc.y);
            acc.z = fmaf(a, b4.z, acc.z); acc.w = fmaf(a, b4.w, acc.w);
          }
          ((float4*)rr)[y * 6 + zq] = acc;
        }
        __syncthreads();
        if (tid < 192) {
          int x = tid >> 3, c = tid & 7;
          const float4* e4 = (const float4*)(etL + x * 576 + c * 72);
          const float4* r4 = (const float4*)(rr + c * 72);
          float a0 = 0, a1 = 0;
#pragma unroll
          for (int q = 0; q < 18; q += 2) {
            float4 e = e4[q], r = r4[q];
            a0 = fmaf(e.x, r.x, fmaf(e.y, r.y, fmaf(e.z, r.z, fmaf(e.w, r.w, a0))));
            float4 e2 = e4[q + 1], r2 = r4[q + 1];
            a1 = fmaf(e2.x, r2.x, fmaf(e2.y, r2.y, fmaf(e2.z, r2.z, fmaf(e2.w, r2.w, a1))));
          }
          red2[tid] = a0 + a1;
        }
        __syncthreads();
        if (tid < 24) {
          float a = 0;
          for (int q = 0; q < 8; q++) a += red2[tid * 8 + q];
          bbase[tri(i, j) * 24 + tid] = M + __logf(fmaxf(a, EPSV));
        }
      }
      batch_bar(bcnt, tgt); tgt += 32;
    }
  }
  // logZ available now
  if (local == 0 && tid == 0) {
    logZg[b] = bbase[496 * 24];
    __hip_atomic_fetch_add(done, 1u, __ATOMIC_RELEASE, __HIP_MEMORY_SCOPE_AGENT);
  }

  //================ outside: 31 levels, block = parent local ================
  {
    float* w = wk;            // 576
    float* ebL = wk + 576;    // 744
    float* ebR = wk + 1320;   // 744
    float* mLs = wk + 2064;   // 32
    float* mRs = wk + 2096;   // 32
    float* ea24 = wk + 2128;  // 24
    float* scal = wk + 2320;  // 16
    for (int l = 32; l >= 2; l--) {
      int S = l - 1, P = 33 - l;
      if (local < P) {
        int i = local, j = i + S, SN = S * 24;
        if (tid < 32) {
          float av = NEGV;
          if (tid < 24) av = la2(aLb[tri(i, j) * 24 + tid], aRb[tri(i, j) * 24 + tid]);
          float m = av;
          for (int off = 16; off; off >>= 1) m = fmaxf(m, __shfl_xor(m, off));
          if (tid < 24) ea24[tid] = __expf(av - m);
          if (tid == 0) scal[0] = m;
        }
        __syncthreads();
        float ma = scal[0];
        if (tid < 144) {
          int y = tid / 6, zq = tid % 6;
          float4 acc = make_float4(0, 0, 0, 0);
#pragma unroll 4
          for (int x = 0; x < 24; x++) {
            float a = ea24[x];
            float4 e = ((const float4*)(etL + x * 576 + y * 24))[zq];
            acc.x = fmaf(a, e.x, acc.x); acc.y = fmaf(a, e.y, acc.y);
            acc.z = fmaf(a, e.z, acc.z); acc.w = fmaf(a, e.w, acc.w);
          }
          ((float4*)w)[y * 6 + zq] = acc;
        }
        for (int idx = tid; idx < SN; idx += 256) {
          int s = idx / 24, c = idx - s * 24;
          ebL[idx] = bbase[tri(i, i + s) * 24 + c];
          ebR[idx] = bbase[tri(i + s + 1, j) * 24 + c];
        }
        __syncthreads();
        if (tid < 8 * S) {
          int s = tid >> 3, q = tid & 7, y0 = q * 3;
          float pl = fmaxf(fmaxf(ebL[s * 24 + y0], ebL[s * 24 + y0 + 1]), ebL[s * 24 + y0 + 2]);
          float pr = fmaxf(fmaxf(ebR[s * 24 + y0], ebR[s * 24 + y0 + 1]), ebR[s * 24 + y0 + 2]);
          for (int off = 4; off; off >>= 1) {
            pl = fmaxf(pl, __shfl_xor(pl, off));
            pr = fmaxf(pr, __shfl_xor(pr, off));
          }
          if (q == 0) { mLs[s] = pl; mRs[s] = pr; }
        }
        __syncthreads();
        for (int idx = tid; idx < SN; idx += 256) {
          int s = idx / 24;
          ebL[idx] = __expf(ebL[idx] - mLs[s]);
          ebR[idx] = __expf(ebR[idx] - mRs[s]);
        }
        __syncthreads();
        for (int u = tid; u < 2 * SN; u += 256) {
          if (u < SN) {  // cL -> aL[tri(i,i+s)][y], unique writer per level
            int s = u / 24, y = u - s * 24;
            const float4* w4 = (const float4*)(w + y * 24);
            const float4* r4 = (const float4*)(ebR + s * 24);
            float acc = 0;
#pragma unroll
            for (int q = 0; q < 6; q++) {
              float4 a = w4[q], c4 = r4[q];
              acc = fmaf(a.x, c4.x, fmaf(a.y, c4.y, fmaf(a.z, c4.z, fmaf(a.w, c4.w, acc))));
            }
            float val = __logf(fmaxf(acc, EPSV)) + ma + mRs[s];
            float* t = aLb + tri(i, i + s) * 24 + y;
            *t = la2(*t, val);
          } else {       // cR -> aR[tri(i+s+1,j)][z]
            int u2 = u - SN;
            int s = u2 / 24, z = u2 - s * 24;
            float acc = 0;
            for (int y = 0; y < 24; y++) acc = fmaf(w[y * 24 + z], ebL[s * 24 + y], acc);
            float val = __logf(fmaxf(acc, EPSV)) + ma + mLs[s];
            float* t = aRb + tri(i + s + 1, j) * 24 + z;
            *t = la2(*t, val);
          }
        }
      }
      batch_bar(bcnt, tgt); tgt += 32;
    }
  }

  //================ mask logits + loss (block = (b, v-chunk local)) ================
  {
    float* p = wk;  // 768, layout [n*32 + t]
    float logZv = bbase[496 * 24];
    for (int c = tid; c < 768; c += 256) {
      int n = c >> 5, t = c & 31;
      int d = tri(t, t) * 24 + n;
      p[c] = __expf(la2(aLb[d], aRb[d]) + bbase[d] - logZv);
    }
    __syncthreads();
    int vbase = local * 1000;
    for (int pass = 0; pass < 2; pass++) {
      int o0 = tid + pass * 512, o1 = o0 + 256;
      bool v0ok = o0 < 1000, v1ok = o1 < 1000;
      int v0 = vbase + o0, v1 = vbase + o1;
      float vr0[24], vr1[24];
#pragma unroll
      for (int n = 0; n < 24; n++) {
        vr0[n] = v0ok ? vocab[n * 32000 + v0] : 0.f;
        vr1[n] = v1ok ? vocab[n * 32000 + v1] : 0.f;
      }
      float* ob0 = out + (size_t)b * 32 * 32000 + v0;
      float* ob1 = out + (size_t)b * 32 * 32000 + v1;
      for (int t4 = 0; t4 < 32; t4 += 4) {
        float a00 = 1e-6f, a01 = 1e-6f, a02 = 1e-6f, a03 = 1e-6f;
        float a10 = 1e-6f, a11 = 1e-6f, a12 = 1e-6f, a13 = 1e-6f;
#pragma unroll 6
        for (int n = 0; n < 24; n++) {
          float4 pv = *(const float4*)(p + n * 32 + t4);
          a00 = fmaf(pv.x, vr0[n], a00); a01 = fmaf(pv.y, vr0[n], a01);
          a02 = fmaf(pv.z, vr0[n], a02); a03 = fmaf(pv.w, vr0[n], a03);
          a10 = fmaf(pv.x, vr1[n], a10); a11 = fmaf(pv.y, vr1[n], a11);
          a12 = fmaf(pv.z, vr1[n], a12); a13 = fmaf(pv.w, vr1[n], a13);
        }
        if (v0ok) {
          ob0[(size_t)(t4 + 0) * 32000] = __logf(a00);
          ob0[(size_t)(t4 + 1) * 32000] = __logf(a01);
          ob0[(size_t)(t4 + 2) * 32000] = __logf(a02);
          ob0[(size_t)(t4 + 3) * 32000] = __logf(a03);
        }
        if (v1ok) {
          ob1[(size_t)(t4 + 0) * 32000] = __logf(a10);
          ob1[(size_t)(t4 + 1) * 32000] = __logf(a11);
          ob1[(size_t)(t4 + 2) * 32000] = __logf(a12);
          ob1[(size_t)(t4 + 3) * 32000] = __logf(a13);
        }
      }
    }
    if (b == 0 && local == 0 && tid == 0) {
      while (__hip_atomic_load(done, __ATOMIC_RELAXED, __HIP_MEMORY_SCOPE_AGENT) < 16u)
        __builtin_amdgcn_s_sleep(2);
      (void)__hip_atomic_load(done, __ATOMIC_ACQUIRE, __HIP_MEMORY_SCOPE_AGENT);
      float s = 0;
      for (int q = 0; q < 16; q++) s += logZg[q];
      out[16384000] = -s / 16.0f;
    }
  }
}

// ---------------------------------------------------------------- launch
extern "C" void kernel_launch(void* const* d_in, const int* in_sizes, int n_in,
                              void* d_out, int out_size, void* d_ws, size_t ws_size,
                              hipStream_t stream) {
  (void)in_sizes; (void)n_in; (void)out_size; (void)ws_size;
  const float* g_seq = (const float*)d_in[0];
  const float* Theta = (const float*)d_in[1];
  const float* vocab = (const float*)d_in[2];
  const float* lng   = (const float*)d_in[3];
  const float* lnb   = (const float*)d_in[4];
  const float* W1    = (const float*)d_in[5];
  const float* bb1   = (const float*)d_in[6];
  const float* W2    = (const float*)d_in[7];
  const float* bb2   = (const float*)d_in[8];
  float* out = (float*)d_out;

  float* ws = (float*)d_ws;
  unsigned* cnt = (unsigned*)d_ws;       // [0..1023] barrier counters (memset 0)
  float* logZg = ws + 1024;              // 16
  float* et_g  = ws + 2048;              // 13824
  float* beta_g = ws + 16384;            // 16*12672 = 202752
  float* aL_g  = beta_g + 202752;
  float* aR_g  = aL_g + 202752;

  hipMemsetAsync(d_ws, 0, 4096, stream);

  void* args[] = {(void*)&g_seq, (void*)&Theta, (void*)&vocab, (void*)&lng,
                  (void*)&lnb, (void*)&W1, (void*)&bb1, (void*)&W2, (void*)&bb2,
                  (void*)&out, (void*)&et_g, (void*)&beta_g, (void*)&aL_g,
                  (void*)&aR_g, (void*)&cnt, (void*)&logZg};
  hipLaunchCooperativeKernel((const void*)mega_kernel, dim3(512), dim3(256),
                             args, 0, stream);
}

// Round 4
// 532.980 us; speedup vs baseline: 6.3065x; 1.8686x over previous
//
#include <hip/hip_runtime.h>
#include <math.h>

#define NEGV -1000000000.0f
#define EPSV 1e-38f

constexpr int BSTRIDE = 528 * 32;   // beta floats per batch (128B-padded cells)
constexpr int ASTRIDE = 528 * 24;   // aL/aR floats per batch

__device__ __forceinline__ int tri(int i, int j) { return ((j * (j + 1)) >> 1) + i; }
__device__ __forceinline__ float la2(float a, float c) {
  float mx = fmaxf(a, c), mn = fminf(a, c);
  return mx + log1pf(__expf(mn - mx));
}
// relaxed agent-scope (sc1) data ops — bypass L1/L2, hit coherent point
__device__ __forceinline__ void gstore(float* p, float v) {
  __hip_atomic_store(p, v, __ATOMIC_RELAXED, __HIP_MEMORY_SCOPE_AGENT);
}
__device__ __forceinline__ float gload(const float* p) {
  return __hip_atomic_load(p, __ATOMIC_RELAXED, __HIP_MEMORY_SCOPE_AGENT);
}
// light barrier primitives: no release/acquire fences (no L2 wb/inv).
// arrive: drain own vmem (sc1 stores acked at coherent point), then relaxed add.
__device__ __forceinline__ void arrive(unsigned* c) {
  __builtin_amdgcn_s_waitcnt(0);
  __hip_atomic_fetch_add(c, 1u, __ATOMIC_RELAXED, __HIP_MEMORY_SCOPE_AGENT);
}
__device__ __forceinline__ void wait_ge(unsigned* c, unsigned tgt) {
  while (__hip_atomic_load(c, __ATOMIC_RELAXED, __HIP_MEMORY_SCOPE_AGENT) < tgt)
    __builtin_amdgcn_s_sleep(1);
}

// 512 blocks x 256 threads. b = blk&15, local = blk>>4.
__global__ void __launch_bounds__(256, 2) mega_kernel(
    const float* __restrict__ g_seq, const float* __restrict__ Theta,
    const float* __restrict__ vocab, const float* __restrict__ lng,
    const float* __restrict__ lnb, const float* __restrict__ W1,
    const float* __restrict__ bb1, const float* __restrict__ W2,
    const float* __restrict__ bb2, float* __restrict__ out,
    float* __restrict__ et_g, float* __restrict__ beta_g,
    float* __restrict__ aL_g, float* __restrict__ aR_g,
    unsigned* __restrict__ cnt, float* __restrict__ logZg) {
  __shared__ __align__(16) float sm[16160];
  float* etL = sm;          // 13824
  float* wk = sm + 13824;   // 2336
  const int tid = threadIdx.x;
  const int blk = blockIdx.x;
  const int b = blk & 15, local = blk >> 4;
  unsigned* gcnt = cnt;
  unsigned* done = cnt + 32;
  unsigned* bcnt = cnt + 64 + b * 32;
  float* bbase = beta_g + b * BSTRIDE;
  float* aLb = aL_g + b * ASTRIDE;
  float* aRb = aR_g + b * ASTRIDE;

  //================ phase 0: frontend (task bt = blk) ================
  {
    float* g = wk;                       // 512
    float2* red = (float2*)(wk + 512);   // 512
    float* hb = wk + 1024;               // 128
    float* ob = wk + 1152;               // 32
    float* sc = wk + 1184;               // 8
    int bt = blk;
    float2 raw = ((const float2*)(g_seq + (size_t)bt * 512))[tid];
    red[tid] = make_float2(raw.x + raw.y, raw.x * raw.x + raw.y * raw.y);
    __syncthreads();
    if (tid < 128) { float2 o = red[tid + 128], m = red[tid]; red[tid] = make_float2(m.x + o.x, m.y + o.y); }
    __syncthreads();
    if (tid < 64) {
      float2 v = red[tid], o = red[tid + 64];
      v.x += o.x; v.y += o.y;
      for (int off = 32; off; off >>= 1) { v.x += __shfl_xor(v.x, off); v.y += __shfl_xor(v.y, off); }
      if (tid == 0) {
        float mu = v.x / 512.0f;
        float var = v.y / 512.0f - mu * mu;
        sc[0] = mu; sc[1] = rsqrtf(var + 1e-5f);
      }
    }
    __syncthreads();
    float mu = sc[0], rstd = sc[1];
    g[2 * tid]     = (raw.x - mu) * rstd * lng[2 * tid]     + lnb[2 * tid];
    g[2 * tid + 1] = (raw.y - mu) * rstd * lng[2 * tid + 1] + lnb[2 * tid + 1];
    __syncthreads();
    {
      int j = tid & 127, hh = tid >> 7, c0 = hh * 256;
      float a0 = 0, a1 = 0, a2 = 0, a3 = 0;
      for (int c = 0; c < 256; c += 4) {
        a0 = fmaf(g[c0 + c],     W1[(c0 + c) * 128 + j],     a0);
        a1 = fmaf(g[c0 + c + 1], W1[(c0 + c + 1) * 128 + j], a1);
        a2 = fmaf(g[c0 + c + 2], W1[(c0 + c + 2) * 128 + j], a2);
        a3 = fmaf(g[c0 + c + 3], W1[(c0 + c + 3) * 128 + j], a3);
      }
      ((float*)red)[tid] = (a0 + a1) + (a2 + a3);
    }
    __syncthreads();
    if (tid < 128) {
      float a = ((float*)red)[tid] + ((float*)red)[tid + 128] + bb1[tid];
      hb[tid] = 0.5f * a * (1.0f + erff(a * 0.70710678118654752f));
    }
    __syncthreads();
    if (tid < 192) {
      int n = tid >> 3, q = tid & 7;
      float a = 0;
      for (int k = 0; k < 16; k++) a = fmaf(hb[q * 16 + k], W2[(q * 16 + k) * 24 + n], a);
      ((float*)red)[tid] = a;
    }
    __syncthreads();
    if (tid < 24) {
      float a = bb2[tid];
      for (int q = 0; q < 8; q++) a += ((float*)red)[tid * 8 + q];
      ob[tid] = a;
    }
    __syncthreads();
    if (tid == 0) {
      float m = ob[0];
      for (int n = 1; n < 24; n++) m = fmaxf(m, ob[n]);
      float s = 0;
      for (int n = 0; n < 24; n++) s += __expf(ob[n] - m);
      sc[2] = m + __logf(s);
    }
    __syncthreads();
    if (tid < 24) {
      int fb = blk >> 5, ft = blk & 31;
      gstore(beta_g + (size_t)fb * BSTRIDE + tri(ft, ft) * 32 + tid, ob[tid] - sc[2]);
    }
  }
  // theta rows (tm dropped: exact — score adds log back; et = exp(theta_log) <= 1)
  if (tid < 64) {
    int z = tid & 31;
    bool up = tid >= 32;
    int row = up ? (512 + blk) : blk;
    bool valid = (!up) || (blk < 64);
    float v = (z < 24 && valid) ? Theta[row * 24 + z] : NEGV;
    float m = v;
    for (int off = 16; off; off >>= 1) m = fmaxf(m, __shfl_xor(m, off));
    float e = (z < 24 && valid) ? __expf(v - m) : 0.f;
    float s = e;
    for (int off = 16; off; off >>= 1) s += __shfl_xor(s, off);
    float lse = m + __logf(s);
    if (z < 24 && valid) gstore(et_g + row * 24 + z, __expf(v - lse));
  }
  // alpha init (aL||aR contiguous); root aL[b][tri(0,31)][0] = 0
  for (int idx = blk * 256 + tid; idx < 2 * 16 * ASTRIDE; idx += 131072) {
    float v = NEGV;
    if (idx < 16 * ASTRIDE && (idx % ASTRIDE) == 11904) v = 0.f;
    gstore(aL_g + idx, v);
  }
  // ---- light global barrier ----
  __syncthreads();
  if (tid == 0) { arrive(gcnt); wait_ge(gcnt, 512u); }
  __syncthreads();

  // stage et into LDS once (fresh lines -> plain vectorized loads are safe)
  for (int i4 = tid; i4 < 3456; i4 += 256)
    ((float4*)etL)[i4] = ((const float4*)et_g)[i4];
  __syncthreads();

  unsigned cum = 0;

  //================ inside: 31 levels, participant-counted barriers ================
  {
    float* eA = wk;           // 744
    float* eB = wk + 744;     // 744
    float* rr = wk + 1488;    // 576
    float* red2 = wk + 2064;  // 192
    float* mrl = wk + 2256;   // 32
    float* msm = wk + 2288;   // 32
    float* scal = wk + 2320;  // 16
    for (int l = 2; l <= 32; l++) {
      int S = l - 1, P = 33 - l;
      if (local < P) {
        if (cum) { if (tid == 0) wait_ge(bcnt, cum); __syncthreads(); }
        int i = local, j = i + S, SN = S * 24;
        for (int idx4 = tid; idx4 < 6 * S; idx4 += 256) {
          int s = idx4 / 6, q = idx4 - 6 * s;
          ((float4*)eA)[idx4] = ((const float4*)(bbase + (size_t)tri(i, i + s) * 32))[q];
          ((float4*)eB)[idx4] = ((const float4*)(bbase + (size_t)tri(i + s + 1, j) * 32))[q];
        }
        __syncthreads();
        if (tid < 8 * S) {
          int s = tid >> 3, q = tid & 7, y0 = q * 3;
          float pa = fmaxf(fmaxf(eA[s * 24 + y0], eA[s * 24 + y0 + 1]), eA[s * 24 + y0 + 2]);
          float pb = fmaxf(fmaxf(eB[s * 24 + y0], eB[s * 24 + y0 + 1]), eB[s * 24 + y0 + 2]);
          for (int off = 4; off; off >>= 1) {
            pa = fmaxf(pa, __shfl_xor(pa, off));
            pb = fmaxf(pb, __shfl_xor(pb, off));
          }
          if (q == 0) { mrl[s] = pb; msm[s] = pa + pb; }
        }
        __syncthreads();
        if (tid < 32) {
          float v = (tid < S) ? msm[tid] : NEGV;
          for (int off = 16; off; off >>= 1) v = fmaxf(v, __shfl_xor(v, off));
          if (tid == 0) scal[0] = v;
        }
        __syncthreads();
        float M = scal[0];
        for (int idx = tid; idx < SN; idx += 256) {
          int s = idx / 24;
          float m_ = mrl[s];
          eA[idx] = __expf(eA[idx] + m_ - M);
          eB[idx] = __expf(eB[idx] - m_);
        }
        __syncthreads();
        if (tid < 144) {
          int y = tid / 6, zq = tid % 6;
          float4 acc = make_float4(0, 0, 0, 0);
          for (int s = 0; s < S; s++) {
            float a = eA[s * 24 + y];
            float4 b4 = ((float4*)eB)[s * 6 + zq];
            acc.x = fmaf(a, b4.x, acc.x); acc.y = fmaf(a, b4.y, acc.y);
            acc.z = fmaf(a, b4.z, acc.z); acc.w = fmaf(a, b4.w, acc.w);
          }
          ((float4*)rr)[y * 6 + zq] = acc;
        }
        __syncthreads();
        if (tid < 192) {
          int x = tid >> 3, c = tid & 7;
          const float4* e4 = (const float4*)(etL + x * 576 + c * 72);
          const float4* r4 = (const float4*)(rr + c * 72);
          float a0 = 0, a1 = 0;
#pragma unroll
          for (int q = 0; q < 18; q += 2) {
            float4 e = e4[q], r = r4[q];
            a0 = fmaf(e.x, r.x, fmaf(e.y, r.y, fmaf(e.z, r.z, fmaf(e.w, r.w, a0))));
            float4 e2 = e4[q + 1], r2 = r4[q + 1];
            a1 = fmaf(e2.x, r2.x, fmaf(e2.y, r2.y, fmaf(e2.z, r2.z, fmaf(e2.w, r2.w, a1))));
          }
          red2[tid] = a0 + a1;
        }
        __syncthreads();
        if (tid < 24) {
          float a = 0;
          for (int q = 0; q < 8; q++) a += red2[tid * 8 + q];
          gstore(bbase + (size_t)tri(i, j) * 32 + tid, M + __logf(fmaxf(a, EPSV)));
        }
        __syncthreads();
        if (tid == 0) arrive(bcnt);
      }
      cum += (unsigned)P;
    }
  }
  if (local == 0 && tid == 0) {
    gstore(logZg + b, gload(bbase + 496 * 32));
    arrive(done);
  }

  //================ outside: 31 levels ================
  {
    float* w = wk;            // 576
    float* ebL = wk + 576;    // 744
    float* ebR = wk + 1320;   // 744
    float* mLs = wk + 2064;   // 32
    float* mRs = wk + 2096;   // 32
    float* ea24 = wk + 2128;  // 24
    float* scal = wk + 2320;  // 16
    for (int l = 32; l >= 2; l--) {
      int S = l - 1, P = 33 - l;
      if (local < P) {
        if (tid == 0) wait_ge(bcnt, cum);
        __syncthreads();
        int i = local, j = i + S, SN = S * 24;
        if (tid < 32) {
          float av = NEGV;
          if (tid < 24) av = la2(gload(aLb + tri(i, j) * 24 + tid), gload(aRb + tri(i, j) * 24 + tid));
          float m = av;
          for (int off = 16; off; off >>= 1) m = fmaxf(m, __shfl_xor(m, off));
          if (tid < 24) ea24[tid] = __expf(av - m);
          if (tid == 0) scal[0] = m;
        }
        __syncthreads();
        float ma = scal[0];
        if (tid < 144) {
          int y = tid / 6, zq = tid % 6;
          float4 acc = make_float4(0, 0, 0, 0);
#pragma unroll 4
          for (int x = 0; x < 24; x++) {
            float a = ea24[x];
            float4 e = ((const float4*)(etL + x * 576 + y * 24))[zq];
            acc.x = fmaf(a, e.x, acc.x); acc.y = fmaf(a, e.y, acc.y);
            acc.z = fmaf(a, e.z, acc.z); acc.w = fmaf(a, e.w, acc.w);
          }
          ((float4*)w)[y * 6 + zq] = acc;
        }
        for (int idx4 = tid; idx4 < 6 * S; idx4 += 256) {
          int s = idx4 / 6, q = idx4 - 6 * s;
          ((float4*)ebL)[idx4] = ((const float4*)(bbase + (size_t)tri(i, i + s) * 32))[q];
          ((float4*)ebR)[idx4] = ((const float4*)(bbase + (size_t)tri(i + s + 1, j) * 32))[q];
        }
        __syncthreads();
        if (tid < 8 * S) {
          int s = tid >> 3, q = tid & 7, y0 = q * 3;
          float pl = fmaxf(fmaxf(ebL[s * 24 + y0], ebL[s * 24 + y0 + 1]), ebL[s * 24 + y0 + 2]);
          float pr = fmaxf(fmaxf(ebR[s * 24 + y0], ebR[s * 24 + y0 + 1]), ebR[s * 24 + y0 + 2]);
          for (int off = 4; off; off >>= 1) {
            pl = fmaxf(pl, __shfl_xor(pl, off));
            pr = fmaxf(pr, __shfl_xor(pr, off));
          }
          if (q == 0) { mLs[s] = pl; mRs[s] = pr; }
        }
        __syncthreads();
        for (int idx = tid; idx < SN; idx += 256) {
          int s = idx / 24;
          ebL[idx] = __expf(ebL[idx] - mLs[s]);
          ebR[idx] = __expf(ebR[idx] - mRs[s]);
        }
        __syncthreads();
        for (int u = tid; u < 2 * SN; u += 256) {
          if (u < SN) {  // cL -> aL[tri(i,i+s)][y]; unique writer per level
            int s = u / 24, y = u - s * 24;
            const float4* w4 = (const float4*)(w + y * 24);
            const float4* r4 = (const float4*)(ebR + s * 24);
            float acc = 0;
#pragma unroll
            for (int q = 0; q < 6; q++) {
              float4 a = w4[q], c4 = r4[q];
              acc = fmaf(a.x, c4.x, fmaf(a.y, c4.y, fmaf(a.z, c4.z, fmaf(a.w, c4.w, acc))));
            }
            float val = __logf(fmaxf(acc, EPSV)) + ma + mRs[s];
            float* t = aLb + tri(i, i + s) * 24 + y;
            gstore(t, la2(gload(t), val));
          } else {       // cR -> aR[tri(i+s+1,j)][z]
            int u2 = u - SN;
            int s = u2 / 24, z = u2 - s * 24;
            float acc = 0;
            for (int y = 0; y < 24; y++) acc = fmaf(w[y * 24 + z], ebL[s * 24 + y], acc);
            float val = __logf(fmaxf(acc, EPSV)) + ma + mLs[s];
            float* t = aRb + tri(i + s + 1, j) * 24 + z;
            gstore(t, la2(gload(t), val));
          }
        }
        __syncthreads();
        if (tid == 0) arrive(bcnt);
      }
      cum += (unsigned)P;
    }
  }
  if (tid == 0) wait_ge(bcnt, cum);
  __syncthreads();

  //================ mask logits + loss ================
  {
    float* p = wk;  // 768, layout [n*32 + t]
    float logZv = gload(bbase + 496 * 32);
    for (int c = tid; c < 768; c += 256) {
      int n = c >> 5, t = c & 31;
      int dA = tri(t, t) * 24 + n;
      float al = gload(aLb + dA), ar = gload(aRb + dA);
      p[c] = __expf(la2(al, ar) + bbase[(size_t)tri(t, t) * 32 + n] - logZv);
    }
    __syncthreads();
    int vbase = local * 1000;
    for (int pass = 0; pass < 2; pass++) {
      int o0 = tid + pass * 512, o1 = o0 + 256;
      bool v0ok = o0 < 1000, v1ok = o1 < 1000;
      int v0 = vbase + o0, v1 = vbase + o1;
      float vr0[24], vr1[24];
#pragma unroll
      for (int n = 0; n < 24; n++) {
        vr0[n] = v0ok ? vocab[n * 32000 + v0] : 0.f;
        vr1[n] = v1ok ? vocab[n * 32000 + v1] : 0.f;
      }
      float* ob0 = out + (size_t)b * 32 * 32000 + v0;
      float* ob1 = out + (size_t)b * 32 * 32000 + v1;
      for (int t4 = 0; t4 < 32; t4 += 4) {
        float a00 = 1e-6f, a01 = 1e-6f, a02 = 1e-6f, a03 = 1e-6f;
        float a10 = 1e-6f, a11 = 1e-6f, a12 = 1e-6f, a13 = 1e-6f;
#pragma unroll 6
        for (int n = 0; n < 24; n++) {
          float4 pv = *(const float4*)(p + n * 32 + t4);
          a00 = fmaf(pv.x, vr0[n], a00); a01 = fmaf(pv.y, vr0[n], a01);
          a02 = fmaf(pv.z, vr0[n], a02); a03 = fmaf(pv.w, vr0[n], a03);
          a10 = fmaf(pv.x, vr1[n], a10); a11 = fmaf(pv.y, vr1[n], a11);
          a12 = fmaf(pv.z, vr1[n], a12); a13 = fmaf(pv.w, vr1[n], a13);
        }
        if (v0ok) {
          ob0[(size_t)(t4 + 0) * 32000] = __logf(a00);
          ob0[(size_t)(t4 + 1) * 32000] = __logf(a01);
          ob0[(size_t)(t4 + 2) * 32000] = __logf(a02);
          ob0[(size_t)(t4 + 3) * 32000] = __logf(a03);
        }
        if (v1ok) {
          ob1[(size_t)(t4 + 0) * 32000] = __logf(a10);
          ob1[(size_t)(t4 + 1) * 32000] = __logf(a11);
          ob1[(size_t)(t4 + 2) * 32000] = __logf(a12);
          ob1[(size_t)(t4 + 3) * 32000] = __logf(a13);
        }
      }
    }
    if (blk == 0 && tid == 0) {
      wait_ge(done, 16u);
      float s = 0;
      for (int q = 0; q < 16; q++) s += gload(logZg + q);
      out[16384000] = -s / 16.0f;
    }
  }
}

// ---------------------------------------------------------------- launch
extern "C" void kernel_launch(void* const* d_in, const int* in_sizes, int n_in,
                              void* d_out, int out_size, void* d_ws, size_t ws_size,
                              hipStream_t stream) {
  (void)in_sizes; (void)n_in; (void)out_size; (void)ws_size;
  const float* g_seq = (const float*)d_in[0];
  const float* Theta = (const float*)d_in[1];
  const float* vocab = (const float*)d_in[2];
  const float* lng   = (const float*)d_in[3];
  const float* lnb   = (const float*)d_in[4];
  const float* W1    = (const float*)d_in[5];
  const float* bb1   = (const float*)d_in[6];
  const float* W2    = (const float*)d_in[7];
  const float* bb2   = (const float*)d_in[8];
  float* out = (float*)d_out;

  float* ws = (float*)d_ws;
  unsigned* cnt = (unsigned*)d_ws;            // counters (memset 0 below)
  float* logZg  = ws + 1024;                  // 16
  float* et_g   = ws + 2048;                  // 13824
  float* beta_g = ws + 16384;                 // 16 * 16896 = 270336
  float* aL_g   = beta_g + 16 * BSTRIDE;      // 202752
  float* aR_g   = aL_g + 16 * ASTRIDE;        // 202752

  hipMemsetAsync(d_ws, 0, 4096, stream);

  void* args[] = {(void*)&g_seq, (void*)&Theta, (void*)&vocab, (void*)&lng,
                  (void*)&lnb, (void*)&W1, (void*)&bb1, (void*)&W2, (void*)&bb2,
                  (void*)&out, (void*)&et_g, (void*)&beta_g, (void*)&aL_g,
                  (void*)&aR_g, (void*)&cnt, (void*)&logZg};
  hipLaunchCooperativeKernel((const void*)mega_kernel, dim3(512), dim3(256),
                             args, 0, stream);
}